// Round 3
// baseline (141.590 us; speedup 1.0000x reference)
//
#include <hip/hip_runtime.h>
#include <hip/hip_bf16.h>

#define NN 4096
#define DD 128
#define MARGIN_F 0.3f
#define JC 64                       // columns per block
#define GX (NN / JC)                // 64
#define GY (NN / 128)               // 32 (each block covers 128 rows = 4 waves * 32)
#define NBLOCKS (GX * GY)           // 2048

typedef __attribute__((ext_vector_type(8))) short bf16x8;   // 8 bf16 = 4 VGPRs
typedef __attribute__((ext_vector_type(4))) float f32x4;

// ws layout:
//   [0 .. 1MB)   p1b (4096*128 bf16)
//   [1MB .. 2MB) p2b
//   then fp32:   a2[N], b2[N], c[N], rowmax[N] (uint), sumacc, donecnt

__device__ __forceinline__ ushort f2bf(float f) {
  __hip_bfloat16 h = __float2bfloat16(f);   // RNE
  return *reinterpret_cast<ushort*>(&h);
}

// Fused: bf16 conversion + row stats + workspace init. One wave per row.
__global__ __launch_bounds__(256) void ptl_prep(
    const float* __restrict__ p1, const float* __restrict__ p2,
    ushort* __restrict__ p1b, ushort* __restrict__ p2b,
    float* __restrict__ a2, float* __restrict__ b2, float* __restrict__ c,
    unsigned int* __restrict__ rowmax, float* __restrict__ sumacc,
    unsigned int* __restrict__ donecnt) {
  int row = blockIdx.x * 4 + (threadIdx.x >> 6);
  int lane = threadIdx.x & 63;
  float2 x = ((const float2*)(p1 + (size_t)row * DD))[lane];
  float2 y = ((const float2*)(p2 + (size_t)row * DD))[lane];
  ushort2 xb, yb;
  xb.x = f2bf(x.x); xb.y = f2bf(x.y);
  yb.x = f2bf(y.x); yb.y = f2bf(y.y);
  ((ushort2*)(p1b + (size_t)row * DD))[lane] = xb;
  ((ushort2*)(p2b + (size_t)row * DD))[lane] = yb;
  float sa = x.x * x.x + x.y * x.y;
  float sb = y.x * y.x + y.y * y.y;
  float d0 = x.x - y.x, d1 = x.y - y.y;
  float sd = d0 * d0 + d1 * d1;
#pragma unroll
  for (int off = 32; off > 0; off >>= 1) {
    sa += __shfl_down(sa, off);
    sb += __shfl_down(sb, off);
    sd += __shfl_down(sd, off);
  }
  if (lane == 0) {
    a2[row] = sa;
    b2[row] = sb;
    c[row] = sd - sa + MARGIN_F;   // dist_ap - ||p1_i||^2 + margin
    rowmax[row] = 0u;              // uint bits of nonneg float
  }
  if (blockIdx.x == 0 && threadIdx.x == 0) {
    *sumacc = 0.f;
    *donecnt = 0u;
  }
}

// LDS-free MFMA sweep, 32 rows/wave (2 strips), fused last-block finalize.
// A/B frags gather row*128 + quad*8 (NT). C layout: col=lane&15, row=quad*4+reg.
__global__ __launch_bounds__(256) void ptl_mfma(
    const ushort* __restrict__ p1b, const ushort* __restrict__ p2b,
    const float* __restrict__ a2v, const float* __restrict__ b2v,
    const float* __restrict__ cvv, unsigned int* __restrict__ rowmax,
    float* __restrict__ sumacc, unsigned int* __restrict__ donecnt,
    float* __restrict__ out) {
  const int tid = threadIdx.x;
  const int w = tid >> 6;
  const int lane = tid & 63;
  const int col16 = lane & 15;
  const int quad = lane >> 4;
  const int rowBase = (blockIdx.y * 4 + w) * 32;
  const int jBase = blockIdx.x * JC;

  __shared__ float wsum[4];
  __shared__ float wm[4];
  __shared__ unsigned int ticket;

  // A fragments for both strips, all K (k = s*32 + quad*8 + j)
  bf16x8 afr[2][4];
#pragma unroll
  for (int st = 0; st < 2; ++st) {
    const ushort* pa = p1b + (size_t)(rowBase + st * 16 + col16) * DD + quad * 8;
#pragma unroll
    for (int s = 0; s < 4; ++s) afr[st][s] = *(const bf16x8*)(pa + s * 32);
  }

  float cv[2][4];
#pragma unroll
  for (int st = 0; st < 2; ++st)
#pragma unroll
    for (int r = 0; r < 4; ++r) cv[st][r] = cvv[rowBase + st * 16 + quad * 4 + r];

  float rmax[2][4] = {{0.f, 0.f, 0.f, 0.f}, {0.f, 0.f, 0.f, 0.f}};
  float lsum = 0.f;

#pragma unroll
  for (int jt = 0; jt < JC / 16; ++jt) {
    const int jcol = jBase + jt * 16 + col16;
    const ushort* pb1 = p1b + (size_t)jcol * DD + quad * 8;
    const ushort* pb2 = p2b + (size_t)jcol * DD + quad * 8;
    bf16x8 bf1[4], bf2[4];
#pragma unroll
    for (int s = 0; s < 4; ++s) {
      bf1[s] = *(const bf16x8*)(pb1 + s * 32);
      bf2[s] = *(const bf16x8*)(pb2 + s * 32);
    }
    f32x4 acc[2][2];
#pragma unroll
    for (int st = 0; st < 2; ++st)
#pragma unroll
      for (int m = 0; m < 2; ++m) acc[st][m] = (f32x4){0.f, 0.f, 0.f, 0.f};
#pragma unroll
    for (int s = 0; s < 4; ++s) {
      acc[0][0] = __builtin_amdgcn_mfma_f32_16x16x32_bf16(afr[0][s], bf1[s], acc[0][0], 0, 0, 0);
      acc[1][0] = __builtin_amdgcn_mfma_f32_16x16x32_bf16(afr[1][s], bf1[s], acc[1][0], 0, 0, 0);
      acc[0][1] = __builtin_amdgcn_mfma_f32_16x16x32_bf16(afr[0][s], bf2[s], acc[0][1], 0, 0, 0);
      acc[1][1] = __builtin_amdgcn_mfma_f32_16x16x32_bf16(afr[1][s], bf2[s], acc[1][1], 0, 0, 0);
    }
    const float aj = a2v[jcol];
    const float bj = b2v[jcol];
#pragma unroll
    for (int st = 0; st < 2; ++st) {
      const bool diagT = (jBase + jt * 16) == (rowBase + st * 16);
#pragma unroll
      for (int r = 0; r < 4; ++r) {
        float v1 = fmaxf(fmaf(2.f, acc[st][0][r], cv[st][r] - aj), 0.f);
        float v2 = fmaxf(fmaf(2.f, acc[st][1][r], cv[st][r] - bj), 0.f);
        if (diagT && col16 == quad * 4 + r) { v1 = 0.f; v2 = 0.f; }
        lsum += v1 + v2;
        rmax[st][r] = fmaxf(rmax[st][r], fmaxf(v1, v2));
      }
    }
  }

  // row-max across the 16 col lanes of each quad (xor<16 stays in-group)
#pragma unroll
  for (int off = 8; off > 0; off >>= 1)
#pragma unroll
    for (int st = 0; st < 2; ++st)
#pragma unroll
      for (int r = 0; r < 4; ++r)
        rmax[st][r] = fmaxf(rmax[st][r], __shfl_xor(rmax[st][r], off));
  if (col16 == 0) {
#pragma unroll
    for (int st = 0; st < 2; ++st)
#pragma unroll
      for (int r = 0; r < 4; ++r)
        atomicMax(&rowmax[rowBase + st * 16 + quad * 4 + r],
                  __float_as_uint(rmax[st][r]));
  }

  // block sum -> one atomicAdd, then ticket
#pragma unroll
  for (int off = 32; off > 0; off >>= 1) lsum += __shfl_down(lsum, off);
  if (lane == 0) wsum[w] = lsum;
  __syncthreads();
  if (tid == 0) {
    atomicAdd(sumacc, wsum[0] + wsum[1] + wsum[2] + wsum[3]);
    __threadfence();
    ticket = atomicAdd(donecnt, 1u);
  }
  __syncthreads();

  // last block finalizes (atomic reads -> coherent across XCDs)
  if (ticket == NBLOCKS - 1) {
    __threadfence();
    float sm = 0.f;
#pragma unroll 4
    for (int i = tid; i < NN; i += 256)
      sm += __uint_as_float(atomicMax(&rowmax[i], 0u));
#pragma unroll
    for (int off = 32; off > 0; off >>= 1) sm += __shfl_down(sm, off);
    if (lane == 0) wm[w] = sm;
    __syncthreads();
    if (tid == 0) {
      float total = atomicAdd(sumacc, 0.f);
      out[0] = (wm[0] + wm[1] + wm[2] + wm[3]) / (float)NN;
      out[1] = total / (2.0f * (float)NN * (float)(NN - 1));
    }
  }
}

extern "C" void kernel_launch(void* const* d_in, const int* in_sizes, int n_in,
                              void* d_out, int out_size, void* d_ws, size_t ws_size,
                              hipStream_t stream) {
  const float* p1 = (const float*)d_in[0];
  const float* p2 = (const float*)d_in[1];
  ushort* p1b = (ushort*)d_ws;
  ushort* p2b = p1b + (size_t)NN * DD;
  float* a2 = (float*)(p2b + (size_t)NN * DD);
  float* b2 = a2 + NN;
  float* c = b2 + NN;
  unsigned int* rowmax = (unsigned int*)(c + NN);
  float* sumacc = (float*)(rowmax + NN);
  unsigned int* donecnt = (unsigned int*)(sumacc + 1);

  ptl_prep<<<NN / 4, 256, 0, stream>>>(p1, p2, p1b, p2b, a2, b2, c,
                                       rowmax, sumacc, donecnt);

  dim3 grid(GX, GY);  // (64, 32)
  ptl_mfma<<<grid, 256, 0, stream>>>(p1b, p2b, a2, b2, c, rowmax, sumacc,
                                     donecnt, (float*)d_out);
}

// Round 4
// 113.395 us; speedup vs baseline: 1.2486x; 1.2486x over previous
//
#include <hip/hip_runtime.h>
#include <hip/hip_bf16.h>

#define NN 4096
#define DD 128
#define MARGIN_F 0.3f
#define JC 128                    // columns per block
#define GX (NN / JC)              // 32
#define GY (NN / 128)             // 32 (block = 4 waves * 32 rows)
#define NBLOCKS (GX * GY)         // 1024
#define NT (JC / 16)              // 8 j-tiles per wave

typedef __attribute__((ext_vector_type(8))) short bf16x8;   // 8 bf16 = 4 VGPRs
typedef __attribute__((ext_vector_type(4))) float f32x4;

// ws layout:
//   [0 .. 1MB)   p1b (4096*128 bf16)
//   [1MB .. 2MB) p2b
//   then fp32:   a2[N], b2[N], c[N], rowmax[N] (uint), sumacc, donecnt

__device__ __forceinline__ ushort f2bf(float f) {
  __hip_bfloat16 h = __float2bfloat16(f);   // RNE
  return *reinterpret_cast<ushort*>(&h);
}

// Fused: bf16 conversion + row stats + workspace init. One wave per row.
__global__ __launch_bounds__(256) void ptl_prep(
    const float* __restrict__ p1, const float* __restrict__ p2,
    ushort* __restrict__ p1b, ushort* __restrict__ p2b,
    float* __restrict__ a2, float* __restrict__ b2, float* __restrict__ c,
    unsigned int* __restrict__ rowmax, float* __restrict__ sumacc,
    unsigned int* __restrict__ donecnt) {
  int row = blockIdx.x * 4 + (threadIdx.x >> 6);
  int lane = threadIdx.x & 63;
  float2 x = ((const float2*)(p1 + (size_t)row * DD))[lane];
  float2 y = ((const float2*)(p2 + (size_t)row * DD))[lane];
  ushort2 xb, yb;
  xb.x = f2bf(x.x); xb.y = f2bf(x.y);
  yb.x = f2bf(y.x); yb.y = f2bf(y.y);
  ((ushort2*)(p1b + (size_t)row * DD))[lane] = xb;
  ((ushort2*)(p2b + (size_t)row * DD))[lane] = yb;
  float sa = x.x * x.x + x.y * x.y;
  float sb = y.x * y.x + y.y * y.y;
  float d0 = x.x - y.x, d1 = x.y - y.y;
  float sd = d0 * d0 + d1 * d1;
#pragma unroll
  for (int off = 32; off > 0; off >>= 1) {
    sa += __shfl_down(sa, off);
    sb += __shfl_down(sb, off);
    sd += __shfl_down(sd, off);
  }
  if (lane == 0) {
    a2[row] = sa;
    b2[row] = sb;
    c[row] = sd - sa + MARGIN_F;   // dist_ap - ||p1_i||^2 + margin
    rowmax[row] = 0u;              // uint bits of nonneg float
  }
  if (blockIdx.x == 0 && threadIdx.x == 0) {
    *sumacc = 0.f;
    *donecnt = 0u;
  }
}

// LDS-free MFMA sweep, 32 rows/wave, register-double-buffered B prefetch.
// A/B frags gather row*128 + quad*8 (NT). C layout: col=lane&15, row=quad*4+reg.
__global__ __launch_bounds__(256) void ptl_mfma(
    const ushort* __restrict__ p1b, const ushort* __restrict__ p2b,
    const float* __restrict__ a2v, const float* __restrict__ b2v,
    const float* __restrict__ cvv, unsigned int* __restrict__ rowmax,
    float* __restrict__ sumacc, unsigned int* __restrict__ donecnt,
    float* __restrict__ out) {
  const int tid = threadIdx.x;
  const int w = tid >> 6;
  const int lane = tid & 63;
  const int col16 = lane & 15;
  const int quad = lane >> 4;
  const int rowBase = (blockIdx.y * 4 + w) * 32;
  const int jBase = blockIdx.x * JC;

  __shared__ float wsum[4];
  __shared__ float wm[4];
  __shared__ unsigned int ticket;

  // A fragments, both strips, full K (k = s*32 + quad*8 + j)
  bf16x8 afr[2][4];
#pragma unroll
  for (int st = 0; st < 2; ++st) {
    const ushort* pa = p1b + (size_t)(rowBase + st * 16 + col16) * DD + quad * 8;
#pragma unroll
    for (int s = 0; s < 4; ++s) afr[st][s] = *(const bf16x8*)(pa + s * 32);
  }

  float cv[2][4];
#pragma unroll
  for (int st = 0; st < 2; ++st)
#pragma unroll
    for (int r = 0; r < 4; ++r) cv[st][r] = cvv[rowBase + st * 16 + quad * 4 + r];

  const ushort* pb1 = p1b + (size_t)(jBase + col16) * DD + quad * 8;
  const ushort* pb2 = p2b + (size_t)(jBase + col16) * DD + quad * 8;

  // Preload tile 0
  bf16x8 b1c[4], b2c[4];
#pragma unroll
  for (int s = 0; s < 4; ++s) {
    b1c[s] = *(const bf16x8*)(pb1 + s * 32);
    b2c[s] = *(const bf16x8*)(pb2 + s * 32);
  }
  float ajc = a2v[jBase + col16];
  float bjc = b2v[jBase + col16];

  float rmax[2][4] = {{0.f, 0.f, 0.f, 0.f}, {0.f, 0.f, 0.f, 0.f}};
  float lsum = 0.f;

#pragma unroll
  for (int jt = 0; jt < NT; ++jt) {
    // Prefetch tile jt+1 into the other register set (issues before MFMAs)
    bf16x8 b1n[4], b2n[4];
    float ajn = 0.f, bjn = 0.f;
    if (jt + 1 < NT) {
      const ushort* q1 = pb1 + (size_t)(jt + 1) * 16 * DD;
      const ushort* q2 = pb2 + (size_t)(jt + 1) * 16 * DD;
#pragma unroll
      for (int s = 0; s < 4; ++s) {
        b1n[s] = *(const bf16x8*)(q1 + s * 32);
        b2n[s] = *(const bf16x8*)(q2 + s * 32);
      }
      ajn = a2v[jBase + (jt + 1) * 16 + col16];
      bjn = b2v[jBase + (jt + 1) * 16 + col16];
    }

    f32x4 acc[2][2];
#pragma unroll
    for (int st = 0; st < 2; ++st)
#pragma unroll
      for (int m = 0; m < 2; ++m) acc[st][m] = (f32x4){0.f, 0.f, 0.f, 0.f};
#pragma unroll
    for (int s = 0; s < 4; ++s) {
      acc[0][0] = __builtin_amdgcn_mfma_f32_16x16x32_bf16(afr[0][s], b1c[s], acc[0][0], 0, 0, 0);
      acc[1][0] = __builtin_amdgcn_mfma_f32_16x16x32_bf16(afr[1][s], b1c[s], acc[1][0], 0, 0, 0);
      acc[0][1] = __builtin_amdgcn_mfma_f32_16x16x32_bf16(afr[0][s], b2c[s], acc[0][1], 0, 0, 0);
      acc[1][1] = __builtin_amdgcn_mfma_f32_16x16x32_bf16(afr[1][s], b2c[s], acc[1][1], 0, 0, 0);
    }

#pragma unroll
    for (int st = 0; st < 2; ++st) {
      const bool diagT = (jBase + jt * 16) == (rowBase + st * 16);
#pragma unroll
      for (int r = 0; r < 4; ++r) {
        float v1 = fmaxf(fmaf(2.f, acc[st][0][r], cv[st][r] - ajc), 0.f);
        float v2 = fmaxf(fmaf(2.f, acc[st][1][r], cv[st][r] - bjc), 0.f);
        if (diagT && col16 == quad * 4 + r) { v1 = 0.f; v2 = 0.f; }
        lsum += v1 + v2;
        rmax[st][r] = fmaxf(rmax[st][r], fmaxf(v1, v2));   // v_max3
      }
    }

    // rotate double buffer (register renames after unroll)
    if (jt + 1 < NT) {
#pragma unroll
      for (int s = 0; s < 4; ++s) { b1c[s] = b1n[s]; b2c[s] = b2n[s]; }
      ajc = ajn; bjc = bjn;
    }
  }

  // row-max across the 16 col lanes of each quad (xor<16 stays in-group)
#pragma unroll
  for (int off = 8; off > 0; off >>= 1)
#pragma unroll
    for (int st = 0; st < 2; ++st)
#pragma unroll
      for (int r = 0; r < 4; ++r)
        rmax[st][r] = fmaxf(rmax[st][r], __shfl_xor(rmax[st][r], off));
  if (col16 == 0) {
#pragma unroll
    for (int st = 0; st < 2; ++st)
#pragma unroll
      for (int r = 0; r < 4; ++r)
        atomicMax(&rowmax[rowBase + st * 16 + quad * 4 + r],
                  __float_as_uint(rmax[st][r]));
  }

  // block sum -> one atomicAdd, then ticket
#pragma unroll
  for (int off = 32; off > 0; off >>= 1) lsum += __shfl_down(lsum, off);
  if (lane == 0) wsum[w] = lsum;
  __syncthreads();
  if (tid == 0) {
    atomicAdd(sumacc, wsum[0] + wsum[1] + wsum[2] + wsum[3]);
    __threadfence();
    ticket = atomicAdd(donecnt, 1u);
  }
  __syncthreads();

  // last block finalizes (atomic reads -> coherent across XCDs)
  if (ticket == NBLOCKS - 1) {
    __threadfence();
    float sm = 0.f;
#pragma unroll 4
    for (int i = tid; i < NN; i += 256)
      sm += __uint_as_float(atomicMax(&rowmax[i], 0u));
#pragma unroll
    for (int off = 32; off > 0; off >>= 1) sm += __shfl_down(sm, off);
    if (lane == 0) wm[w] = sm;
    __syncthreads();
    if (tid == 0) {
      float total = atomicAdd(sumacc, 0.f);
      out[0] = (wm[0] + wm[1] + wm[2] + wm[3]) / (float)NN;
      out[1] = total / (2.0f * (float)NN * (float)(NN - 1));
    }
  }
}

extern "C" void kernel_launch(void* const* d_in, const int* in_sizes, int n_in,
                              void* d_out, int out_size, void* d_ws, size_t ws_size,
                              hipStream_t stream) {
  const float* p1 = (const float*)d_in[0];
  const float* p2 = (const float*)d_in[1];
  ushort* p1b = (ushort*)d_ws;
  ushort* p2b = p1b + (size_t)NN * DD;
  float* a2 = (float*)(p2b + (size_t)NN * DD);
  float* b2 = a2 + NN;
  float* c = b2 + NN;
  unsigned int* rowmax = (unsigned int*)(c + NN);
  float* sumacc = (float*)(rowmax + NN);
  unsigned int* donecnt = (unsigned int*)(sumacc + 1);

  ptl_prep<<<NN / 4, 256, 0, stream>>>(p1, p2, p1b, p2b, a2, b2, c,
                                       rowmax, sumacc, donecnt);

  dim3 grid(GX, GY);  // (32, 32)
  ptl_mfma<<<grid, 256, 0, stream>>>(p1b, p2b, a2, b2, c, rowmax, sumacc,
                                     donecnt, (float*)d_out);
}

// Round 5
// 98.187 us; speedup vs baseline: 1.4420x; 1.1549x over previous
//
#include <hip/hip_runtime.h>
#include <hip/hip_bf16.h>

#define NN 4096
#define DD 128
#define MARGIN_F 0.3f
#define JC 128                    // columns per block
#define GX (NN / JC)              // 32
#define GY (NN / 128)             // 32 (block = 4 waves * 32 rows)
#define NBLOCKS (GX * GY)         // 1024
#define NT (JC / 16)              // 8 j-tiles per wave

typedef __attribute__((ext_vector_type(8))) short bf16x8;   // 8 bf16 = 4 VGPRs
typedef __attribute__((ext_vector_type(4))) float f32x4;
typedef __attribute__((ext_vector_type(2))) float f32x2;

// Panel-swizzled bf16 layout (ushort units), one 16-row panel = 2048 ushorts:
//   element (row, k) -> (row/16)*2048 + (k/32)*512 + ((k%32)/8)*128
//                       + (row%16)*8 + (k%8)
// A wave's MFMA fragment load (lane = quad*16 + col16, 16B each) is then a
// single fully-coalesced 1KB transaction: quad*256B + col16*16B contiguous.
//
// ws layout:
//   [0 .. 1MB)   p1t (swizzled bf16)
//   [1MB .. 2MB) p2t
//   then fp32:   a2[N], b2[N], c[N], rowmax[N] (uint), sumacc, donecnt

__device__ __forceinline__ ushort f2bf(float f) {
  __hip_bfloat16 h = __float2bfloat16(f);   // RNE
  return *reinterpret_cast<ushort*>(&h);
}

// Fused: bf16 convert+swizzle + row stats + workspace init. One wave per row.
__global__ __launch_bounds__(256) void ptl_prep(
    const float* __restrict__ p1, const float* __restrict__ p2,
    ushort* __restrict__ p1t, ushort* __restrict__ p2t,
    float* __restrict__ a2, float* __restrict__ b2, float* __restrict__ c,
    unsigned int* __restrict__ rowmax, float* __restrict__ sumacc,
    unsigned int* __restrict__ donecnt) {
  int row = blockIdx.x * 4 + (threadIdx.x >> 6);
  int lane = threadIdx.x & 63;
  float2 x = ((const float2*)(p1 + (size_t)row * DD))[lane];
  float2 y = ((const float2*)(p2 + (size_t)row * DD))[lane];
  ushort2 xb, yb;
  xb.x = f2bf(x.x); xb.y = f2bf(x.y);
  yb.x = f2bf(y.x); yb.y = f2bf(y.y);
  // swizzled store of (row, k) and (row, k+1), k = 2*lane (j even -> same 4B)
  int k = lane * 2;
  size_t idx = (size_t)(row >> 4) * 2048 + (size_t)(k >> 5) * 512 +
               (size_t)((k & 31) >> 3) * 128 + (size_t)(row & 15) * 8 +
               (size_t)(k & 7);
  *(ushort2*)(p1t + idx) = xb;
  *(ushort2*)(p2t + idx) = yb;

  float sa = x.x * x.x + x.y * x.y;
  float sb = y.x * y.x + y.y * y.y;
  float d0 = x.x - y.x, d1 = x.y - y.y;
  float sd = d0 * d0 + d1 * d1;
#pragma unroll
  for (int off = 32; off > 0; off >>= 1) {
    sa += __shfl_down(sa, off);
    sb += __shfl_down(sb, off);
    sd += __shfl_down(sd, off);
  }
  if (lane == 0) {
    a2[row] = sa;
    b2[row] = sb;
    c[row] = sd - sa + MARGIN_F;   // dist_ap - ||p1_i||^2 + margin
    rowmax[row] = 0u;              // uint bits of nonneg float
  }
  if (blockIdx.x == 0 && threadIdx.x == 0) {
    *sumacc = 0.f;
    *donecnt = 0u;
  }
}

// LDS-free MFMA sweep, 32 rows/wave, coalesced swizzled fragment loads,
// float2-packed epilogue, fused last-block finalize.
// C layout: col = lane&15, row = quad*4 + reg.
__global__ __launch_bounds__(256) void ptl_mfma(
    const ushort* __restrict__ p1t, const ushort* __restrict__ p2t,
    const float* __restrict__ a2v, const float* __restrict__ b2v,
    const float* __restrict__ cvv, unsigned int* __restrict__ rowmax,
    float* __restrict__ sumacc, unsigned int* __restrict__ donecnt,
    float* __restrict__ out) {
  const int tid = threadIdx.x;
  const int w = tid >> 6;
  const int lane = tid & 63;
  const int col16 = lane & 15;
  const int quad = lane >> 4;
  const int rowBase = (blockIdx.y * 4 + w) * 32;
  const int jBase = blockIdx.x * JC;
  const int lofs = quad * 128 + col16 * 8;   // lane offset within a panel

  __shared__ float wsum[4];
  __shared__ float wm[4];
  __shared__ unsigned int ticket;

  // A fragments, both strips, full K — coalesced panel loads
  bf16x8 afr[2][4];
#pragma unroll
  for (int st = 0; st < 2; ++st) {
    const ushort* pa = p1t + ((size_t)(rowBase >> 4) + st) * 2048 + lofs;
#pragma unroll
    for (int s = 0; s < 4; ++s) afr[st][s] = *(const bf16x8*)(pa + s * 512);
  }

  float cv[2][4];
#pragma unroll
  for (int st = 0; st < 2; ++st)
#pragma unroll
    for (int r = 0; r < 4; ++r) cv[st][r] = cvv[rowBase + st * 16 + quad * 4 + r];

  const ushort* pb1 = p1t + (size_t)(jBase >> 4) * 2048 + lofs;
  const ushort* pb2 = p2t + (size_t)(jBase >> 4) * 2048 + lofs;

  f32x2 lsum2 = {0.f, 0.f};
  f32x2 rmax2[2][4];
#pragma unroll
  for (int st = 0; st < 2; ++st)
#pragma unroll
    for (int r = 0; r < 4; ++r) rmax2[st][r] = (f32x2){0.f, 0.f};

#pragma unroll
  for (int jt = 0; jt < NT; ++jt) {
    bf16x8 b1[4], b2[4];
#pragma unroll
    for (int s = 0; s < 4; ++s) {
      b1[s] = *(const bf16x8*)(pb1 + (size_t)jt * 2048 + s * 512);
      b2[s] = *(const bf16x8*)(pb2 + (size_t)jt * 2048 + s * 512);
    }
    f32x4 acc[2][2];
#pragma unroll
    for (int st = 0; st < 2; ++st)
#pragma unroll
      for (int m = 0; m < 2; ++m) acc[st][m] = (f32x4){0.f, 0.f, 0.f, 0.f};
#pragma unroll
    for (int s = 0; s < 4; ++s) {
      acc[0][0] = __builtin_amdgcn_mfma_f32_16x16x32_bf16(afr[0][s], b1[s], acc[0][0], 0, 0, 0);
      acc[1][0] = __builtin_amdgcn_mfma_f32_16x16x32_bf16(afr[1][s], b1[s], acc[1][0], 0, 0, 0);
      acc[0][1] = __builtin_amdgcn_mfma_f32_16x16x32_bf16(afr[0][s], b2[s], acc[0][1], 0, 0, 0);
      acc[1][1] = __builtin_amdgcn_mfma_f32_16x16x32_bf16(afr[1][s], b2[s], acc[1][1], 0, 0, 0);
    }

    const int jcol = jBase + jt * 16 + col16;
    f32x2 nj = { a2v[jcol], b2v[jcol] };
#pragma unroll
    for (int st = 0; st < 2; ++st) {
      const bool diagT = (jBase + jt * 16) == (rowBase + st * 16);
#pragma unroll
      for (int r = 0; r < 4; ++r) {
        f32x2 t = { acc[st][0][r], acc[st][1][r] };
        f32x2 v = t * 2.f + (cv[st][r] - nj);   // packed fma candidates
        v.x = fmaxf(v.x, 0.f);
        v.y = fmaxf(v.y, 0.f);
        if (diagT && col16 == quad * 4 + r) v = (f32x2){0.f, 0.f};
        lsum2 += v;
        rmax2[st][r].x = fmaxf(rmax2[st][r].x, v.x);
        rmax2[st][r].y = fmaxf(rmax2[st][r].y, v.y);
      }
    }
  }

  float lsum = lsum2.x + lsum2.y;
  float rmax[2][4];
#pragma unroll
  for (int st = 0; st < 2; ++st)
#pragma unroll
    for (int r = 0; r < 4; ++r)
      rmax[st][r] = fmaxf(rmax2[st][r].x, rmax2[st][r].y);

  // row-max across the 16 col lanes of each quad (xor<16 stays in-group)
#pragma unroll
  for (int off = 8; off > 0; off >>= 1)
#pragma unroll
    for (int st = 0; st < 2; ++st)
#pragma unroll
      for (int r = 0; r < 4; ++r)
        rmax[st][r] = fmaxf(rmax[st][r], __shfl_xor(rmax[st][r], off));
  if (col16 == 0) {
#pragma unroll
    for (int st = 0; st < 2; ++st)
#pragma unroll
      for (int r = 0; r < 4; ++r)
        atomicMax(&rowmax[rowBase + st * 16 + quad * 4 + r],
                  __float_as_uint(rmax[st][r]));
  }

  // block sum -> one atomicAdd, then ticket
#pragma unroll
  for (int off = 32; off > 0; off >>= 1) lsum += __shfl_down(lsum, off);
  if (lane == 0) wsum[w] = lsum;
  __syncthreads();
  if (tid == 0) {
    atomicAdd(sumacc, wsum[0] + wsum[1] + wsum[2] + wsum[3]);
    __threadfence();
    ticket = atomicAdd(donecnt, 1u);
  }
  __syncthreads();

  // last block finalizes (atomic reads -> coherent across XCDs)
  if (ticket == NBLOCKS - 1) {
    __threadfence();
    float sm = 0.f;
#pragma unroll 4
    for (int i = tid; i < NN; i += 256)
      sm += __uint_as_float(atomicMax(&rowmax[i], 0u));
#pragma unroll
    for (int off = 32; off > 0; off >>= 1) sm += __shfl_down(sm, off);
    if (lane == 0) wm[w] = sm;
    __syncthreads();
    if (tid == 0) {
      float total = atomicAdd(sumacc, 0.f);
      out[0] = (wm[0] + wm[1] + wm[2] + wm[3]) / (float)NN;
      out[1] = total / (2.0f * (float)NN * (float)(NN - 1));
    }
  }
}

extern "C" void kernel_launch(void* const* d_in, const int* in_sizes, int n_in,
                              void* d_out, int out_size, void* d_ws, size_t ws_size,
                              hipStream_t stream) {
  const float* p1 = (const float*)d_in[0];
  const float* p2 = (const float*)d_in[1];
  ushort* p1t = (ushort*)d_ws;
  ushort* p2t = p1t + (size_t)NN * DD;
  float* a2 = (float*)(p2t + (size_t)NN * DD);
  float* b2 = a2 + NN;
  float* c = b2 + NN;
  unsigned int* rowmax = (unsigned int*)(c + NN);
  float* sumacc = (float*)(rowmax + NN);
  unsigned int* donecnt = (unsigned int*)(sumacc + 1);

  ptl_prep<<<NN / 4, 256, 0, stream>>>(p1, p2, p1t, p2t, a2, b2, c,
                                       rowmax, sumacc, donecnt);

  dim3 grid(GX, GY);  // (32, 32)
  ptl_mfma<<<grid, 256, 0, stream>>>(p1t, p2t, a2, b2, c, rowmax, sumacc,
                                     donecnt, (float*)d_out);
}

// Round 6
// 92.838 us; speedup vs baseline: 1.5251x; 1.0576x over previous
//
#include <hip/hip_runtime.h>
#include <hip/hip_bf16.h>

#define NN 4096
#define DD 128
#define MARGIN_F 0.3f
#define JC 128                    // columns per block
#define GX (NN / JC)              // 32
#define GY (NN / 128)             // 32 (block = 4 waves * 32 rows = 128 rows)
#define NBLOCKS (GX * GY)         // 1024
#define NT (JC / 16)              // 8 j-tiles per block

typedef __attribute__((ext_vector_type(8))) short bf16x8;   // 8 bf16 = 4 VGPRs
typedef __attribute__((ext_vector_type(4))) float f32x4;
typedef __attribute__((ext_vector_type(2))) float f32x2;

// Panel-swizzled bf16 layout (ushort units), one 16-row panel = 2048 ushorts:
//   element (row, k) -> (row/16)*2048 + (k/32)*512 + ((k%32)/8)*128
//                       + (row%16)*8 + (k%8)
// A fragment load (lane = quad*16+col16) is one coalesced 1KB transaction,
// and a whole 16-row panel is a CONTIGUOUS 4KB block -> global_load_lds-able.
//
// ws layout:
//   [0 .. 1MB)   p1t (swizzled bf16)
//   [1MB .. 2MB) p2t
//   then fp32:   a2[N], b2[N], c[N], rowmax[N] (uint), sumpart[16], donecnt

__device__ __forceinline__ ushort f2bf(float f) {
  __hip_bfloat16 h = __float2bfloat16(f);   // RNE
  return *reinterpret_cast<ushort*>(&h);
}

// async global->LDS, 16B per lane; lds dest = uniform base + lane*16
__device__ __forceinline__ void gload_lds16(const ushort* g, ushort* l) {
  __builtin_amdgcn_global_load_lds(
      (const __attribute__((address_space(1))) void*)g,
      (__attribute__((address_space(3))) void*)l, 16, 0, 0);
}

// Fused: bf16 convert+swizzle + row stats + workspace init. One wave per row.
__global__ __launch_bounds__(256) void ptl_prep(
    const float* __restrict__ p1, const float* __restrict__ p2,
    ushort* __restrict__ p1t, ushort* __restrict__ p2t,
    float* __restrict__ a2, float* __restrict__ b2, float* __restrict__ c,
    unsigned int* __restrict__ rowmax, float* __restrict__ sumpart,
    unsigned int* __restrict__ donecnt) {
  int row = blockIdx.x * 4 + (threadIdx.x >> 6);
  int lane = threadIdx.x & 63;
  float2 x = ((const float2*)(p1 + (size_t)row * DD))[lane];
  float2 y = ((const float2*)(p2 + (size_t)row * DD))[lane];
  ushort2 xb, yb;
  xb.x = f2bf(x.x); xb.y = f2bf(x.y);
  yb.x = f2bf(y.x); yb.y = f2bf(y.y);
  int k = lane * 2;
  size_t idx = (size_t)(row >> 4) * 2048 + (size_t)(k >> 5) * 512 +
               (size_t)((k & 31) >> 3) * 128 + (size_t)(row & 15) * 8 +
               (size_t)(k & 7);
  *(ushort2*)(p1t + idx) = xb;
  *(ushort2*)(p2t + idx) = yb;

  float sa = x.x * x.x + x.y * x.y;
  float sb = y.x * y.x + y.y * y.y;
  float d0 = x.x - y.x, d1 = x.y - y.y;
  float sd = d0 * d0 + d1 * d1;
#pragma unroll
  for (int off = 32; off > 0; off >>= 1) {
    sa += __shfl_down(sa, off);
    sb += __shfl_down(sb, off);
    sd += __shfl_down(sd, off);
  }
  if (lane == 0) {
    a2[row] = sa;
    b2[row] = sb;
    c[row] = sd - sa + MARGIN_F;   // dist_ap - ||p1_i||^2 + margin
    rowmax[row] = 0u;              // uint bits of nonneg float
  }
  if (blockIdx.x == 0) {
    if (threadIdx.x < 16) sumpart[threadIdx.x] = 0.f;
    if (threadIdx.x == 16) *donecnt = 0u;
  }
}

// MFMA sweep: B-tiles staged in LDS (shared by all 4 waves), double-buffered
// async global_load_lds; A fragments from global (coalesced panel loads).
// C layout: col = lane&15, row = quad*4 + reg.
__global__ __launch_bounds__(256) void ptl_mfma(
    const ushort* __restrict__ p1t, const ushort* __restrict__ p2t,
    const float* __restrict__ a2v, const float* __restrict__ b2v,
    const float* __restrict__ cvv, unsigned int* __restrict__ rowmax,
    float* __restrict__ sumpart, unsigned int* __restrict__ donecnt,
    float* __restrict__ out) {
  const int tid = threadIdx.x;
  const int w = tid >> 6;
  const int lane = tid & 63;
  const int col16 = lane & 15;
  const int quad = lane >> 4;
  const int rowBase = blockIdx.y * 128 + w * 32;
  const int jBase = blockIdx.x * JC;
  const int lofs = quad * 128 + col16 * 8;   // ushort offset within a panel

  __shared__ __align__(16) ushort ldsB[2][2][2048];  // [stage][arr][panel]
  __shared__ float wsum[4];
  __shared__ float wm[4];
  __shared__ unsigned int ticket;

  // B prefetch: wave w stages 2KB of the 8KB (b1,b2) panel pair per tile.
  const int arr = w >> 1;    // 0 -> p1t panel, 1 -> p2t panel
  const int half = w & 1;
  const ushort* gB = (arr ? p2t : p1t) + (size_t)(jBase >> 4) * 2048 +
                     half * 1024 + lane * 8;
  ushort* lB0 = &ldsB[0][arr][half * 1024];
  ushort* lB1 = &ldsB[1][arr][half * 1024];

  // issue tile 0 prefetch immediately
  gload_lds16(gB, lB0);
  gload_lds16(gB + 512, lB0 + 512);

  // A fragments, both strips, full K — coalesced panel loads from global
  bf16x8 afr[2][4];
#pragma unroll
  for (int st = 0; st < 2; ++st) {
    const ushort* pa = p1t + ((size_t)(rowBase >> 4) + st) * 2048 + lofs;
#pragma unroll
    for (int s = 0; s < 4; ++s) afr[st][s] = *(const bf16x8*)(pa + s * 512);
  }

  float cv[2][4];
#pragma unroll
  for (int st = 0; st < 2; ++st)
#pragma unroll
    for (int r = 0; r < 4; ++r) cv[st][r] = cvv[rowBase + st * 16 + quad * 4 + r];

  f32x2 lsum2 = {0.f, 0.f};
  f32x2 rmax2[2][4];
#pragma unroll
  for (int st = 0; st < 2; ++st)
#pragma unroll
    for (int r = 0; r < 4; ++r) rmax2[st][r] = (f32x2){0.f, 0.f};

#pragma unroll
  for (int jt = 0; jt < NT; ++jt) {
    const int cur = jt & 1;
    __syncthreads();   // ldsB[cur] filled (vmcnt drained); ldsB[1-cur] free
    if (jt + 1 < NT) {
      const ushort* g = gB + (size_t)(jt + 1) * 2048;
      ushort* l = cur ? lB0 : lB1;
      gload_lds16(g, l);
      gload_lds16(g + 512, l + 512);
    }

    bf16x8 b1[4], b2[4];
#pragma unroll
    for (int s = 0; s < 4; ++s) {
      b1[s] = *(const bf16x8*)&ldsB[cur][0][s * 512 + lofs];
      b2[s] = *(const bf16x8*)&ldsB[cur][1][s * 512 + lofs];
    }
    f32x4 acc[2][2];
#pragma unroll
    for (int st = 0; st < 2; ++st)
#pragma unroll
      for (int m = 0; m < 2; ++m) acc[st][m] = (f32x4){0.f, 0.f, 0.f, 0.f};
#pragma unroll
    for (int s = 0; s < 4; ++s) {
      acc[0][0] = __builtin_amdgcn_mfma_f32_16x16x32_bf16(afr[0][s], b1[s], acc[0][0], 0, 0, 0);
      acc[1][0] = __builtin_amdgcn_mfma_f32_16x16x32_bf16(afr[1][s], b1[s], acc[1][0], 0, 0, 0);
      acc[0][1] = __builtin_amdgcn_mfma_f32_16x16x32_bf16(afr[0][s], b2[s], acc[0][1], 0, 0, 0);
      acc[1][1] = __builtin_amdgcn_mfma_f32_16x16x32_bf16(afr[1][s], b2[s], acc[1][1], 0, 0, 0);
    }

    const int jcol = jBase + jt * 16 + col16;
    f32x2 nj = { a2v[jcol], b2v[jcol] };
#pragma unroll
    for (int st = 0; st < 2; ++st) {
      const bool diagT = (jBase + jt * 16) == (rowBase + st * 16);
#pragma unroll
      for (int r = 0; r < 4; ++r) {
        f32x2 t = { acc[st][0][r], acc[st][1][r] };
        f32x2 v = t * 2.f + (cv[st][r] - nj);
        v.x = fmaxf(v.x, 0.f);
        v.y = fmaxf(v.y, 0.f);
        if (diagT && col16 == quad * 4 + r) v = (f32x2){0.f, 0.f};
        lsum2 += v;
        rmax2[st][r].x = fmaxf(rmax2[st][r].x, v.x);
        rmax2[st][r].y = fmaxf(rmax2[st][r].y, v.y);
      }
    }
  }

  float lsum = lsum2.x + lsum2.y;
  float rmax[2][4];
#pragma unroll
  for (int st = 0; st < 2; ++st)
#pragma unroll
    for (int r = 0; r < 4; ++r)
      rmax[st][r] = fmaxf(rmax2[st][r].x, rmax2[st][r].y);

  // row-max across the 16 col lanes of each quad (xor<16 stays in-group)
#pragma unroll
  for (int off = 8; off > 0; off >>= 1)
#pragma unroll
    for (int st = 0; st < 2; ++st)
#pragma unroll
      for (int r = 0; r < 4; ++r)
        rmax[st][r] = fmaxf(rmax[st][r], __shfl_xor(rmax[st][r], off));
  if (col16 == 0) {
#pragma unroll
    for (int st = 0; st < 2; ++st)
#pragma unroll
      for (int r = 0; r < 4; ++r)
        atomicMax(&rowmax[rowBase + st * 16 + quad * 4 + r],
                  __float_as_uint(rmax[st][r]));
  }

  // block sum -> 16 distributed accumulator slots (avoid same-address chain)
#pragma unroll
  for (int off = 32; off > 0; off >>= 1) lsum += __shfl_down(lsum, off);
  if (lane == 0) wsum[w] = lsum;
  __syncthreads();
  const int bid = blockIdx.y * GX + blockIdx.x;
  if (tid == 0) {
    atomicAdd(&sumpart[bid & 15], wsum[0] + wsum[1] + wsum[2] + wsum[3]);
    __threadfence();
    ticket = atomicAdd(donecnt, 1u);
  }
  __syncthreads();

  // last block finalizes (atomic reads -> coherent across XCDs)
  if (ticket == NBLOCKS - 1) {
    __threadfence();
    float sm = 0.f;
#pragma unroll 4
    for (int i = tid; i < NN; i += 256)
      sm += __uint_as_float(atomicMax(&rowmax[i], 0u));
#pragma unroll
    for (int off = 32; off > 0; off >>= 1) sm += __shfl_down(sm, off);
    if (lane == 0) wm[w] = sm;
    float sp = 0.f;
    if (w == 0) {
      sp = (lane < 16) ? atomicAdd(&sumpart[lane], 0.f) : 0.f;
#pragma unroll
      for (int off = 8; off > 0; off >>= 1) sp += __shfl_down(sp, off);
    }
    __syncthreads();
    if (tid == 0) {
      out[0] = (wm[0] + wm[1] + wm[2] + wm[3]) / (float)NN;
      out[1] = sp / (2.0f * (float)NN * (float)(NN - 1));
    }
  }
}

extern "C" void kernel_launch(void* const* d_in, const int* in_sizes, int n_in,
                              void* d_out, int out_size, void* d_ws, size_t ws_size,
                              hipStream_t stream) {
  const float* p1 = (const float*)d_in[0];
  const float* p2 = (const float*)d_in[1];
  ushort* p1t = (ushort*)d_ws;
  ushort* p2t = p1t + (size_t)NN * DD;
  float* a2 = (float*)(p2t + (size_t)NN * DD);
  float* b2 = a2 + NN;
  float* c = b2 + NN;
  unsigned int* rowmax = (unsigned int*)(c + NN);
  float* sumpart = (float*)(rowmax + NN);
  unsigned int* donecnt = (unsigned int*)(sumpart + 16);

  ptl_prep<<<NN / 4, 256, 0, stream>>>(p1, p2, p1t, p2t, a2, b2, c,
                                       rowmax, sumpart, donecnt);

  dim3 grid(GX, GY);  // (32, 32)
  ptl_mfma<<<grid, 256, 0, stream>>>(p1t, p2t, a2, b2, c, rowmax, sumpart,
                                     donecnt, (float*)d_out);
}